// Round 12
// baseline (296.904 us; speedup 1.0000x reference)
//
#include <hip/hip_runtime.h>
#include <hip/hip_bf16.h>

#define B_  32
#define S_  512
#define D_  768
#define H_  12
#define HD_ 64
#define QKV_ELEMS (B_ * H_ * S_ * HD_)  // 12582912 per tensor

typedef __hip_bfloat16 bf16;
typedef short bf16x8_t __attribute__((ext_vector_type(8)));
typedef float f32x4_t  __attribute__((ext_vector_type(4)));

__device__ __forceinline__ float bf2f(bf16 x) { return __bfloat162float(x); }
__device__ __forceinline__ bf16  f2bf(float x) { return __float2bfloat16(x); }

__device__ __forceinline__ void gl_lds16(const short* g, short* l) {
    __builtin_amdgcn_global_load_lds(
        (const __attribute__((address_space(1))) void*)g,
        (__attribute__((address_space(3))) void*)l, 16, 0, 0);
}

// ---------------------------------------------------------------------------
// fp32 -> bf16 conversion for the two WEIGHT tensors only (x conversion is
// now fused into qkv's A-staging; saves the 75 MB x pass ~12 us).
// ---------------------------------------------------------------------------
__global__ __launch_bounds__(256) void f2bf2_kernel(
    const float* __restrict__ in0, unsigned short* __restrict__ out0, int n0,
    const float* __restrict__ in1, unsigned short* __restrict__ out1, int n1)
{
    int i = blockIdx.x * 256 + threadIdx.x;
    const float* in; unsigned short* out;
    if (i < n0) { in = in0; out = out0; }
    else        { in = in1; out = out1; i -= n0; if (i >= n1) return; }
    float4 v = reinterpret_cast<const float4*>(in)[i];
    ushort4 o;
    o.x = __bfloat16_as_ushort(f2bf(v.x));
    o.y = __bfloat16_as_ushort(f2bf(v.y));
    o.z = __bfloat16_as_ushort(f2bf(v.z));
    o.w = __bfloat16_as_ushort(f2bf(v.w));
    reinterpret_cast<ushort4*>(out)[i] = o;
}

// ---------------------------------------------------------------------------
// MFMA GEMM core — single-buffered bf16 A+B (round-9/11 measured-best).
// Used by proj (A already bf16).  Permanent lessons encoded here:
//  * gl_lds IS the coalescing mechanism (r10: B-from-global = 2.1x slower).
//  * (256,4) bound: VGPR cap 128, no spill, 4 blocks/CU ((256,5) spills, r8).
//  * single-buffer > dbuf at short K (65.5 vs 75 us, r9 vs r6).
// ---------------------------------------------------------------------------
#define GEMM_CORE(As, Bs, Aptr, Bptr, m0, n0, K)                               \
    const int t = threadIdx.x;                                                 \
    const int w = t >> 6, lane = t & 63;                                       \
    const int wr = w >> 1, wc = w & 1;                                         \
    const int quad = lane >> 4, l16 = lane & 15;                               \
    f32x4_t acc[4][4] = {};                                                    \
    const int lrow = lane >> 3;                                                \
    const int scol = (((lane & 7) ^ (lrow & 7)) * 8);                          \
    _Pragma("unroll")                                                          \
    for (int j = 0; j < 4; ++j) {                                              \
        int R = j * 32 + w * 8;                                                \
        gl_lds16((Aptr) + (size_t)((m0) + R + lrow) * (K) + scol, &(As)[R * 64]); \
        gl_lds16((Bptr) + (size_t)((n0) + R + lrow) * (K) + scol, &(Bs)[R * 64]); \
    }                                                                          \
    for (int k0 = 0; k0 < (K); k0 += 64) {                                     \
        __syncthreads();                                                       \
        _Pragma("unroll")                                                      \
        for (int ks = 0; ks < 64; ks += 32) {                                  \
            bf16x8_t af[4], bf_[4];                                            \
            _Pragma("unroll")                                                  \
            for (int tm = 0; tm < 4; ++tm)                                     \
                af[tm] = *(const bf16x8_t*)&(As)[(wr * 64 + tm * 16 + l16) * 64 \
                        + ((((ks >> 3) + quad) ^ (l16 & 7)) * 8)];             \
            _Pragma("unroll")                                                  \
            for (int tn = 0; tn < 4; ++tn)                                     \
                bf_[tn] = *(const bf16x8_t*)&(Bs)[(wc * 64 + tn * 16 + l16) * 64 \
                        + ((((ks >> 3) + quad) ^ (l16 & 7)) * 8)];             \
            _Pragma("unroll")                                                  \
            for (int tm = 0; tm < 4; ++tm)                                     \
                _Pragma("unroll")                                              \
                for (int tn = 0; tn < 4; ++tn)                                 \
                    acc[tm][tn] = __builtin_amdgcn_mfma_f32_16x16x32_bf16(     \
                        af[tm], bf_[tn], acc[tm][tn], 0, 0, 0);                \
        }                                                                      \
        __syncthreads();                                                       \
        if (k0 + 64 < (K)) {                                                   \
            _Pragma("unroll")                                                  \
            for (int j = 0; j < 4; ++j) {                                      \
                int R = j * 32 + w * 8;                                        \
                gl_lds16((Aptr) + (size_t)((m0) + R + lrow) * (K) + k0 + 64 + scol, \
                         &(As)[R * 64]);                                       \
                gl_lds16((Bptr) + (size_t)((n0) + R + lrow) * (K) + k0 + 64 + scol, \
                         &(Bs)[R * 64]);                                       \
            }                                                                  \
        }                                                                      \
    }

// cvt helper: 8 fp32 -> bf16x8 (same __float2bfloat16 as the old f2bf pass
// -> numerics identical)
#define CVT8(v, f0, f1)                                                        \
    v[0] = (short)__bfloat16_as_ushort(f2bf((f0).x));                          \
    v[1] = (short)__bfloat16_as_ushort(f2bf((f0).y));                          \
    v[2] = (short)__bfloat16_as_ushort(f2bf((f0).z));                          \
    v[3] = (short)__bfloat16_as_ushort(f2bf((f0).w));                          \
    v[4] = (short)__bfloat16_as_ushort(f2bf((f1).x));                          \
    v[5] = (short)__bfloat16_as_ushort(f2bf((f1).y));                          \
    v[6] = (short)__bfloat16_as_ushort(f2bf((f1).z));                          \
    v[7] = (short)__bfloat16_as_ushort(f2bf((f1).w))

// ---------------------------------------------------------------------------
// Kernel 1: QKV projection with FUSED fp32->bf16 A-staging.
// A-staging: global fp32 -> reg (2x float4, coalesced 32 B/lane) -> cvt ->
// ds_write_b128 at the BYTE-IDENTICAL swizzled LDS slot gl_lds16 used
// (As + R*64 + lane*8 shorts).  Short register live-range (all within the
// staging phase, after barrier-2) -> no r8-style spill; in-wave load wait
// covered by 16 waves/CU TLP (same mechanism as r9).  B-staging, MFMA
// phase, epilogue, XCD swizzle byte-identical to r9/r11.
// A fp32 panel (393 KB) is L2-resident across its 18 consecutive n-blocks.
// ---------------------------------------------------------------------------
__global__ __launch_bounds__(256, 4) void qkv_gemm_mfma(
    const float* __restrict__ A, const short* __restrict__ W,
    const float* __restrict__ bias,
    bf16* __restrict__ Q, bf16* __restrict__ Kp, bf16* __restrict__ Vp)
{
    __shared__ short As[128 * 64];   // 16 KB
    __shared__ short Bs[128 * 64];   // 16 KB
    const int bid = blockIdx.x;
    const int swz = (bid & 7) * (2304 / 8) + (bid >> 3);
    const int n0 = (swz % 18) * 128;
    const int m0 = (swz / 18) * 128;

    const int t = threadIdx.x;
    const int w = t >> 6, lane = t & 63;
    const int wr = w >> 1, wc = w & 1;
    const int quad = lane >> 4, l16 = lane & 15;
    f32x4_t acc[4][4] = {};
    const int lrow = lane >> 3;
    const int scol = (((lane & 7) ^ (lrow & 7)) * 8);

    // prologue: A0 fp32->reg->cvt->LDS; B0 gl_lds
#pragma unroll
    for (int j = 0; j < 4; ++j) {
        int R = j * 32 + w * 8;
        const float* src = A + (size_t)(m0 + R + lrow) * 768 + scol;
        float4 f0 = *(const float4*)src;
        float4 f1 = *(const float4*)(src + 4);
        bf16x8_t v; CVT8(v, f0, f1);
        *(bf16x8_t*)&As[R * 64 + lane * 8] = v;
        gl_lds16(W + (size_t)(n0 + R + lrow) * 768 + scol, &Bs[R * 64]);
    }

    for (int k0 = 0; k0 < 768; k0 += 64) {
        __syncthreads();   // drains vmcnt (B gl_lds) + lgkm (A ds_write)
#pragma unroll
        for (int ks = 0; ks < 64; ks += 32) {
            bf16x8_t af[4], bf_[4];
#pragma unroll
            for (int tm = 0; tm < 4; ++tm)
                af[tm] = *(const bf16x8_t*)&As[(wr * 64 + tm * 16 + l16) * 64
                        + ((((ks >> 3) + quad) ^ (l16 & 7)) * 8)];
#pragma unroll
            for (int tn = 0; tn < 4; ++tn)
                bf_[tn] = *(const bf16x8_t*)&Bs[(wc * 64 + tn * 16 + l16) * 64
                        + ((((ks >> 3) + quad) ^ (l16 & 7)) * 8)];
#pragma unroll
            for (int tm = 0; tm < 4; ++tm)
#pragma unroll
                for (int tn = 0; tn < 4; ++tn)
                    acc[tm][tn] = __builtin_amdgcn_mfma_f32_16x16x32_bf16(
                        af[tm], bf_[tn], acc[tm][tn], 0, 0, 0);
        }
        __syncthreads();   // all waves done reading tile k0
        if (k0 + 64 < 768) {
#pragma unroll
            for (int j = 0; j < 4; ++j) {
                int R = j * 32 + w * 8;
                const float* src = A + (size_t)(m0 + R + lrow) * 768 + k0 + 64 + scol;
                float4 f0 = *(const float4*)src;
                float4 f1 = *(const float4*)(src + 4);
                bf16x8_t v; CVT8(v, f0, f1);
                *(bf16x8_t*)&As[R * 64 + lane * 8] = v;
                gl_lds16(W + (size_t)(n0 + R + lrow) * 768 + k0 + 64 + scol, &Bs[R * 64]);
            }
        }
    }

    const int which = n0 / 768;
    const int h = ((n0 + wc * 64) % 768) >> 6;
    bf16* dst = (which == 0) ? Q : (which == 1) ? Kp : Vp;
    float bv[4];
#pragma unroll
    for (int tn = 0; tn < 4; ++tn) bv[tn] = bias[n0 + wc * 64 + tn * 16 + l16];
#pragma unroll
    for (int tm = 0; tm < 4; ++tm) {
#pragma unroll
        for (int r = 0; r < 4; ++r) {
            int m = m0 + wr * 64 + tm * 16 + quad * 4 + r;
            int b = m >> 9, s = m & 511;
            size_t rb = (((size_t)b * H_ + h) * S_ + s) * HD_;
#pragma unroll
            for (int tn = 0; tn < 4; ++tn)
                dst[rb + tn * 16 + l16] = f2bf(acc[tm][tn][r] + bv[tn]);
        }
    }
}

// ---------------------------------------------------------------------------
// Kernel 3: output projection, fp32 out (r9/r11 exact: bf16 A via gl_lds).
// ---------------------------------------------------------------------------
__global__ __launch_bounds__(256, 4) void proj_gemm_mfma(
    const short* __restrict__ A, const short* __restrict__ W,
    const float* __restrict__ bias, float* __restrict__ out)
{
    __shared__ short As[128 * 64];
    __shared__ short Bs[128 * 64];
    const int bid = blockIdx.x;
    const int swz = (bid & 7) * (768 / 8) + (bid >> 3);
    const int n0 = (swz % 6) * 128;
    const int m0 = (swz / 6) * 128;
    GEMM_CORE(As, Bs, A, W, m0, n0, 768)

    float bv[4];
#pragma unroll
    for (int tn = 0; tn < 4; ++tn) bv[tn] = bias[n0 + wc * 64 + tn * 16 + l16];
#pragma unroll
    for (int tm = 0; tm < 4; ++tm) {
#pragma unroll
        for (int r = 0; r < 4; ++r) {
            int m = m0 + wr * 64 + tm * 16 + quad * 4 + r;
#pragma unroll
            for (int tn = 0; tn < 4; ++tn)
                out[(size_t)m * 768 + n0 + wc * 64 + tn * 16 + l16] =
                    acc[tm][tn][r] + bv[tn];
        }
    }
}

// ---------------------------------------------------------------------------
// Kernel 2: MFMA flash attention — pipelined (round-5 measured-good, exact).
// ---------------------------------------------------------------------------
#define QT 128
#define KT 64
#define PS 68
#define VS 68

__global__ __launch_bounds__(256, 3) void attn_mfma(
    const short* __restrict__ Qg, const short* __restrict__ Kg,
    const short* __restrict__ Vg, bf16* __restrict__ O)
{
    __shared__ short Ks[2][KT * 64];   // 16 KB
    __shared__ short Vt[2][64 * VS];   // 17 KB  [dim][key]
    __shared__ short Ps[QT * PS];      // 17 KB

    const int t = threadIdx.x;
    const int w = t >> 6, lane = t & 63;
    const int quad = lane >> 4, l16 = lane & 15;
    const int lrow = lane >> 3;
    const int scol = (((lane & 7) ^ (lrow & 7)) * 8);
    const int bid = blockIdx.x;
    const int bh = (bid & 7) + 8 * (bid >> 5);
    const int qt = (bid >> 3) & 3;
    const int q0 = qt * QT;
    const size_t base = (size_t)bh * (S_ * HD_);
    const int wq = w * 32;

    // Q fragments: direct global->reg, loop-invariant (16 VGPRs).
    bf16x8_t aq[2][2];
#pragma unroll
    for (int tm = 0; tm < 2; ++tm)
#pragma unroll
        for (int ksi = 0; ksi < 2; ++ksi)
            aq[tm][ksi] = *(const bf16x8_t*)(Qg + base
                + (size_t)(q0 + wq + tm * 16 + l16) * 64 + ksi * 32 + quad * 8);

    f32x4_t Oacc[2][4] = {};
    float lsum[2][4] = {};

    // prologue: stage K0 (gl_lds, swizzled) + V0 global->reg->Vt[0]
#pragma unroll
    for (int j = 0; j < 2; ++j) {
        int R = j * 32 + w * 8;
        gl_lds16(Kg + base + (size_t)(R + lrow) * 64 + scol, &Ks[0][R * 64]);
    }
    {
        const bf16x8_t* gv = (const bf16x8_t*)(Vg + base + (size_t)lane * 64 + w * 16);
        bf16x8_t v0 = gv[0], v1 = gv[1];
#pragma unroll
        for (int i = 0; i < 8; ++i) {
            Vt[0][(w * 16 + i) * VS + lane]     = v0[i];
            Vt[0][(w * 16 + 8 + i) * VS + lane] = v1[i];
        }
    }
    __syncthreads();

    for (int kt = 0; kt < 8; ++kt) {
        const int cur = kt & 1, nxt = cur ^ 1;
        bf16x8_t pv0 = {}, pv1 = {};
        if (kt < 7) {
#pragma unroll
            for (int j = 0; j < 2; ++j) {
                int R = j * 32 + w * 8;
                gl_lds16(Kg + base + (size_t)((kt + 1) * KT + R + lrow) * 64 + scol,
                         &Ks[nxt][R * 64]);
            }
            const bf16x8_t* gv = (const bf16x8_t*)(Vg + base
                + (size_t)((kt + 1) * KT + lane) * 64 + w * 16);
            pv0 = gv[0]; pv1 = gv[1];
        }

        // QK^T: per-wave S tile [32 queries x 64 keys]
        f32x4_t sc[2][4] = {};
        __builtin_amdgcn_s_setprio(1);
#pragma unroll
        for (int ks = 0; ks < 64; ks += 32) {
            bf16x8_t bk[4];
#pragma unroll
            for (int tn = 0; tn < 4; ++tn)
                bk[tn] = *(const bf16x8_t*)&Ks[cur][(tn * 16 + l16) * 64
                        + ((((ks >> 3) + quad) ^ (l16 & 7)) * 8)];
#pragma unroll
            for (int tm = 0; tm < 2; ++tm)
#pragma unroll
                for (int tn = 0; tn < 4; ++tn)
                    sc[tm][tn] = __builtin_amdgcn_mfma_f32_16x16x32_bf16(
                        aq[tm][ks >> 5], bk[tn], sc[tm][tn], 0, 0, 0);
        }
        __builtin_amdgcn_s_setprio(0);

        // p = exp(s * 0.125); per-lane row partials; P -> LDS bf16
#pragma unroll
        for (int tm = 0; tm < 2; ++tm) {
#pragma unroll
            for (int r = 0; r < 4; ++r) {
                int row = wq + tm * 16 + quad * 4 + r;
                float rs = 0.f;
#pragma unroll
                for (int tn = 0; tn < 4; ++tn) {
                    float p = __expf(sc[tm][tn][r] * 0.125f);
                    rs += p;
                    Ps[row * PS + tn * 16 + l16] = (short)__bfloat16_as_ushort(f2bf(p));
                }
                lsum[tm][r] += rs;
            }
        }
        // no barrier: Ps rows [wq, wq+32) are written and read by this wave only

        // PV: O[32 x 64] per wave
        __builtin_amdgcn_s_setprio(1);
#pragma unroll
        for (int ks = 0; ks < 64; ks += 32) {
            bf16x8_t ap[2], bv[4];
#pragma unroll
            for (int tm = 0; tm < 2; ++tm)
                ap[tm] = *(const bf16x8_t*)&Ps[(wq + tm * 16 + l16) * PS + ks + quad * 8];
#pragma unroll
            for (int tn = 0; tn < 4; ++tn)
                bv[tn] = *(const bf16x8_t*)&Vt[cur][(tn * 16 + l16) * VS + ks + quad * 8];
#pragma unroll
            for (int tm = 0; tm < 2; ++tm)
#pragma unroll
                for (int tn = 0; tn < 4; ++tn)
                    Oacc[tm][tn] = __builtin_amdgcn_mfma_f32_16x16x32_bf16(
                        ap[tm], bv[tn], Oacc[tm][tn], 0, 0, 0);
        }
        __builtin_amdgcn_s_setprio(0);

        if (kt < 7) {
#pragma unroll
            for (int i = 0; i < 8; ++i) {
                Vt[nxt][(w * 16 + i) * VS + lane]     = pv0[i];
                Vt[nxt][(w * 16 + 8 + i) * VS + lane] = pv1[i];
            }
        }
        __syncthreads();
    }

    // reduce row sums across 16 col-lanes, normalize, store
    float linv[2][4];
#pragma unroll
    for (int tm = 0; tm < 2; ++tm)
#pragma unroll
        for (int r = 0; r < 4; ++r) {
            float v = lsum[tm][r];
            v += __shfl_xor(v, 1, 64);
            v += __shfl_xor(v, 2, 64);
            v += __shfl_xor(v, 4, 64);
            v += __shfl_xor(v, 8, 64);
            linv[tm][r] = 1.f / v;
        }
    const int b = bh / H_, h = bh % H_;
#pragma unroll
    for (int tm = 0; tm < 2; ++tm) {
#pragma unroll
        for (int r = 0; r < 4; ++r) {
            int row = q0 + wq + tm * 16 + quad * 4 + r;
            size_t ob = ((size_t)b * S_ + row) * D_ + h * HD_;
#pragma unroll
            for (int tn = 0; tn < 4; ++tn)
                O[ob + tn * 16 + l16] = f2bf(Oacc[tm][tn][r] * linv[tm][r]);
        }
    }
}

// ---------------------------------------------------------------------------
extern "C" void kernel_launch(void* const* d_in, const int* in_sizes, int n_in,
                              void* d_out, int out_size, void* d_ws, size_t ws_size,
                              hipStream_t stream) {
    const float* x      = (const float*)d_in[0];
    const float* qkv_w  = (const float*)d_in[1];
    const float* qkv_b  = (const float*)d_in[2];
    const float* proj_w = (const float*)d_in[3];
    const float* proj_b = (const float*)d_in[4];
    float* out = (float*)d_out;

    unsigned short* q     = (unsigned short*)d_ws;
    unsigned short* k     = q + QKV_ELEMS;
    unsigned short* v     = k + QKV_ELEMS;
    unsigned short* slot4 = v + QKV_ELEMS;          // attn-out
    unsigned short* wq    = slot4 + QKV_ELEMS;
    unsigned short* wp    = wq + 2304 * 768;

    // weights-only conversion: 1728 + 576 = 2304 blocks (~3 us)
    const int nw1 = 2304 * 768 / 4, nw2 = 768 * 768 / 4;
    f2bf2_kernel<<<(nw1 + nw2 + 255) / 256, 256, 0, stream>>>(
        qkv_w, wq, nw1, proj_w, wp, nw2);

    // qkv reads fp32 x directly (fused conversion in A-staging)
    qkv_gemm_mfma<<<dim3(2304), 256, 0, stream>>>(
        x, (const short*)wq, qkv_b,
        (bf16*)q, (bf16*)k, (bf16*)v);

    attn_mfma<<<dim3(32 * 12 * 4), 256, 0, stream>>>(
        (const short*)q, (const short*)k, (const short*)v, (bf16*)slot4);

    proj_gemm_mfma<<<dim3(768), 256, 0, stream>>>(
        (const short*)slot4, (const short*)wp, proj_b, out);
}

// Round 13
// 243.275 us; speedup vs baseline: 1.2204x; 1.2204x over previous
//
#include <hip/hip_runtime.h>
#include <hip/hip_bf16.h>

#define B_  32
#define S_  512
#define D_  768
#define H_  12
#define HD_ 64
#define QKV_ELEMS (B_ * H_ * S_ * HD_)  // 12582912 per tensor

typedef __hip_bfloat16 bf16;
typedef short bf16x8_t __attribute__((ext_vector_type(8)));
typedef float f32x4_t  __attribute__((ext_vector_type(4)));

__device__ __forceinline__ float bf2f(bf16 x) { return __bfloat162float(x); }
__device__ __forceinline__ bf16  f2bf(float x) { return __float2bfloat16(x); }

__device__ __forceinline__ void gl_lds16(const short* g, short* l) {
    __builtin_amdgcn_global_load_lds(
        (const __attribute__((address_space(1))) void*)g,
        (__attribute__((address_space(3))) void*)l, 16, 0, 0);
}

// ---------------------------------------------------------------------------
// fused fp32 -> bf16 conversion for all three tensors in ONE launch.
// Round-12 lesson (permanent): fusing the x-conversion into qkv's A-staging
// regressed 2x — synchronous global->reg->cvt->ds_write staging exposes the
// wave's own load latency inside lockstep barrier phases (async gl_lds does
// not), and fp32 staging doubles per-step A-bytes.  The standalone
// conversion pass at full HBM BW is cheaper than in-GEMM fusion.
// ---------------------------------------------------------------------------
__global__ __launch_bounds__(256) void f2bf3_kernel(
    const float* __restrict__ in0, unsigned short* __restrict__ out0, int n0,
    const float* __restrict__ in1, unsigned short* __restrict__ out1, int n1,
    const float* __restrict__ in2, unsigned short* __restrict__ out2, int n2)
{
    int i = blockIdx.x * 256 + threadIdx.x;
    const float* in; unsigned short* out;
    if (i < n0)           { in = in0; out = out0; }
    else if (i < n0 + n1) { in = in1; out = out1; i -= n0; }
    else                  { in = in2; out = out2; i -= n0 + n1;
                            if (i >= n2) return; }
    float4 v = reinterpret_cast<const float4*>(in)[i];
    ushort4 o;
    o.x = __bfloat16_as_ushort(f2bf(v.x));
    o.y = __bfloat16_as_ushort(f2bf(v.y));
    o.z = __bfloat16_as_ushort(f2bf(v.z));
    o.w = __bfloat16_as_ushort(f2bf(v.w));
    reinterpret_cast<ushort4*>(out)[i] = o;
}

// ---------------------------------------------------------------------------
// MFMA GEMM core — single-buffered (round-9/11 measured-best, final).
// Permanent lessons encoded:
//  * gl_lds IS the coalescing mechanism (r10: B-from-global = 2.1x slower;
//    per-lane fragment reads scatter a wave across 16 rows = 16 transactions).
//  * async gl_lds staging only (r12: sync reg-staging+cvt = 2x slower).
//  * (256,4) bound: VGPR cap 128, no spill, 4 blocks/CU ((256,5) is an
//    unreachable occupancy bucket -> acc spills to scratch, r8).
//  * single-buffer > dbuf at short K=768 (65.5 vs 75 us, r9 vs r6): 2x
//    blocks/CU of cross-block TLP beats intra-block double-buffering.
// Schedule per K-step: sync (tile resident) -> 32 MFMA -> sync -> stage
// next tile into the same buffer.
// ---------------------------------------------------------------------------
#define GEMM_CORE(As, Bs, Aptr, Bptr, m0, n0, K)                               \
    const int t = threadIdx.x;                                                 \
    const int w = t >> 6, lane = t & 63;                                       \
    const int wr = w >> 1, wc = w & 1;                                         \
    const int quad = lane >> 4, l16 = lane & 15;                               \
    f32x4_t acc[4][4] = {};                                                    \
    const int lrow = lane >> 3;                                                \
    const int scol = (((lane & 7) ^ (lrow & 7)) * 8);                          \
    _Pragma("unroll")                                                          \
    for (int j = 0; j < 4; ++j) {                                              \
        int R = j * 32 + w * 8;                                                \
        gl_lds16((Aptr) + (size_t)((m0) + R + lrow) * (K) + scol, &(As)[R * 64]); \
        gl_lds16((Bptr) + (size_t)((n0) + R + lrow) * (K) + scol, &(Bs)[R * 64]); \
    }                                                                          \
    for (int k0 = 0; k0 < (K); k0 += 64) {                                     \
        __syncthreads();   /* implicit vmcnt drain: tile k0 resident */        \
        _Pragma("unroll")                                                      \
        for (int ks = 0; ks < 64; ks += 32) {                                  \
            bf16x8_t af[4], bf_[4];                                            \
            _Pragma("unroll")                                                  \
            for (int tm = 0; tm < 4; ++tm)                                     \
                af[tm] = *(const bf16x8_t*)&(As)[(wr * 64 + tm * 16 + l16) * 64 \
                        + ((((ks >> 3) + quad) ^ (l16 & 7)) * 8)];             \
            _Pragma("unroll")                                                  \
            for (int tn = 0; tn < 4; ++tn)                                     \
                bf_[tn] = *(const bf16x8_t*)&(Bs)[(wc * 64 + tn * 16 + l16) * 64 \
                        + ((((ks >> 3) + quad) ^ (l16 & 7)) * 8)];             \
            _Pragma("unroll")                                                  \
            for (int tm = 0; tm < 4; ++tm)                                     \
                _Pragma("unroll")                                              \
                for (int tn = 0; tn < 4; ++tn)                                 \
                    acc[tm][tn] = __builtin_amdgcn_mfma_f32_16x16x32_bf16(     \
                        af[tm], bf_[tn], acc[tm][tn], 0, 0, 0);                \
        }                                                                      \
        __syncthreads();   /* all waves done reading tile k0 */                \
        if (k0 + 64 < (K)) {                                                   \
            _Pragma("unroll")                                                  \
            for (int j = 0; j < 4; ++j) {                                      \
                int R = j * 32 + w * 8;                                        \
                gl_lds16((Aptr) + (size_t)((m0) + R + lrow) * (K) + k0 + 64 + scol, \
                         &(As)[R * 64]);                                       \
                gl_lds16((Bptr) + (size_t)((n0) + R + lrow) * (K) + k0 + 64 + scol, \
                         &(Bs)[R * 64]);                                       \
            }                                                                  \
        }                                                                      \
    }

// ---------------------------------------------------------------------------
// Kernel 1: QKV projection -> q/k/v in [B,H,S,HD] bf16.
// 1D grid + bijective XCD swizzle (verified: FETCH 135 -> 67 MB).
// Single-buffer LDS 32 KiB; launch_bounds (256,4): no spill, 4 blocks/CU.
// ---------------------------------------------------------------------------
__global__ __launch_bounds__(256, 4) void qkv_gemm_mfma(
    const short* __restrict__ A, const short* __restrict__ W,
    const float* __restrict__ bias,
    bf16* __restrict__ Q, bf16* __restrict__ Kp, bf16* __restrict__ Vp)
{
    __shared__ short As[128 * 64];   // 16 KB
    __shared__ short Bs[128 * 64];   // 16 KB
    const int bid = blockIdx.x;
    const int swz = (bid & 7) * (2304 / 8) + (bid >> 3);
    const int n0 = (swz % 18) * 128;
    const int m0 = (swz / 18) * 128;
    GEMM_CORE(As, Bs, A, W, m0, n0, 768)

    const int which = n0 / 768;
    const int h = ((n0 + wc * 64) % 768) >> 6;
    bf16* dst = (which == 0) ? Q : (which == 1) ? Kp : Vp;
    float bv[4];
#pragma unroll
    for (int tn = 0; tn < 4; ++tn) bv[tn] = bias[n0 + wc * 64 + tn * 16 + l16];
#pragma unroll
    for (int tm = 0; tm < 4; ++tm) {
#pragma unroll
        for (int r = 0; r < 4; ++r) {
            int m = m0 + wr * 64 + tm * 16 + quad * 4 + r;
            int b = m >> 9, s = m & 511;
            size_t rb = (((size_t)b * H_ + h) * S_ + s) * HD_;
#pragma unroll
            for (int tn = 0; tn < 4; ++tn)
                dst[rb + tn * 16 + l16] = f2bf(acc[tm][tn][r] + bv[tn]);
        }
    }
}

// ---------------------------------------------------------------------------
// Kernel 3: output projection, fp32 out.  Same single-buffer + XCD swizzle.
// ---------------------------------------------------------------------------
__global__ __launch_bounds__(256, 4) void proj_gemm_mfma(
    const short* __restrict__ A, const short* __restrict__ W,
    const float* __restrict__ bias, float* __restrict__ out)
{
    __shared__ short As[128 * 64];
    __shared__ short Bs[128 * 64];
    const int bid = blockIdx.x;
    const int swz = (bid & 7) * (768 / 8) + (bid >> 3);
    const int n0 = (swz % 6) * 128;
    const int m0 = (swz / 6) * 128;
    GEMM_CORE(As, Bs, A, W, m0, n0, 768)

    float bv[4];
#pragma unroll
    for (int tn = 0; tn < 4; ++tn) bv[tn] = bias[n0 + wc * 64 + tn * 16 + l16];
#pragma unroll
    for (int tm = 0; tm < 4; ++tm) {
#pragma unroll
        for (int r = 0; r < 4; ++r) {
            int m = m0 + wr * 64 + tm * 16 + quad * 4 + r;
#pragma unroll
            for (int tn = 0; tn < 4; ++tn)
                out[(size_t)m * 768 + n0 + wc * 64 + tn * 16 + l16] =
                    acc[tm][tn][r] + bv[tn];
        }
    }
}

// ---------------------------------------------------------------------------
// Kernel 2: MFMA flash attention — pipelined (round-5 measured-good, exact).
// ---------------------------------------------------------------------------
#define QT 128
#define KT 64
#define PS 68
#define VS 68

__global__ __launch_bounds__(256, 3) void attn_mfma(
    const short* __restrict__ Qg, const short* __restrict__ Kg,
    const short* __restrict__ Vg, bf16* __restrict__ O)
{
    __shared__ short Ks[2][KT * 64];   // 16 KB
    __shared__ short Vt[2][64 * VS];   // 17 KB  [dim][key]
    __shared__ short Ps[QT * PS];      // 17 KB

    const int t = threadIdx.x;
    const int w = t >> 6, lane = t & 63;
    const int quad = lane >> 4, l16 = lane & 15;
    const int lrow = lane >> 3;
    const int scol = (((lane & 7) ^ (lrow & 7)) * 8);
    const int bid = blockIdx.x;
    const int bh = (bid & 7) + 8 * (bid >> 5);
    const int qt = (bid >> 3) & 3;
    const int q0 = qt * QT;
    const size_t base = (size_t)bh * (S_ * HD_);
    const int wq = w * 32;

    // Q fragments: direct global->reg, loop-invariant (16 VGPRs).
    bf16x8_t aq[2][2];
#pragma unroll
    for (int tm = 0; tm < 2; ++tm)
#pragma unroll
        for (int ksi = 0; ksi < 2; ++ksi)
            aq[tm][ksi] = *(const bf16x8_t*)(Qg + base
                + (size_t)(q0 + wq + tm * 16 + l16) * 64 + ksi * 32 + quad * 8);

    f32x4_t Oacc[2][4] = {};
    float lsum[2][4] = {};

    // prologue: stage K0 (gl_lds, swizzled) + V0 global->reg->Vt[0]
#pragma unroll
    for (int j = 0; j < 2; ++j) {
        int R = j * 32 + w * 8;
        gl_lds16(Kg + base + (size_t)(R + lrow) * 64 + scol, &Ks[0][R * 64]);
    }
    {
        const bf16x8_t* gv = (const bf16x8_t*)(Vg + base + (size_t)lane * 64 + w * 16);
        bf16x8_t v0 = gv[0], v1 = gv[1];
#pragma unroll
        for (int i = 0; i < 8; ++i) {
            Vt[0][(w * 16 + i) * VS + lane]     = v0[i];
            Vt[0][(w * 16 + 8 + i) * VS + lane] = v1[i];
        }
    }
    __syncthreads();

    for (int kt = 0; kt < 8; ++kt) {
        const int cur = kt & 1, nxt = cur ^ 1;
        bf16x8_t pv0 = {}, pv1 = {};
        if (kt < 7) {
#pragma unroll
            for (int j = 0; j < 2; ++j) {
                int R = j * 32 + w * 8;
                gl_lds16(Kg + base + (size_t)((kt + 1) * KT + R + lrow) * 64 + scol,
                         &Ks[nxt][R * 64]);
            }
            const bf16x8_t* gv = (const bf16x8_t*)(Vg + base
                + (size_t)((kt + 1) * KT + lane) * 64 + w * 16);
            pv0 = gv[0]; pv1 = gv[1];
        }

        // QK^T: per-wave S tile [32 queries x 64 keys]
        f32x4_t sc[2][4] = {};
        __builtin_amdgcn_s_setprio(1);
#pragma unroll
        for (int ks = 0; ks < 64; ks += 32) {
            bf16x8_t bk[4];
#pragma unroll
            for (int tn = 0; tn < 4; ++tn)
                bk[tn] = *(const bf16x8_t*)&Ks[cur][(tn * 16 + l16) * 64
                        + ((((ks >> 3) + quad) ^ (l16 & 7)) * 8)];
#pragma unroll
            for (int tm = 0; tm < 2; ++tm)
#pragma unroll
                for (int tn = 0; tn < 4; ++tn)
                    sc[tm][tn] = __builtin_amdgcn_mfma_f32_16x16x32_bf16(
                        aq[tm][ks >> 5], bk[tn], sc[tm][tn], 0, 0, 0);
        }
        __builtin_amdgcn_s_setprio(0);

        // p = exp(s * 0.125); per-lane row partials; P -> LDS bf16
#pragma unroll
        for (int tm = 0; tm < 2; ++tm) {
#pragma unroll
            for (int r = 0; r < 4; ++r) {
                int row = wq + tm * 16 + quad * 4 + r;
                float rs = 0.f;
#pragma unroll
                for (int tn = 0; tn < 4; ++tn) {
                    float p = __expf(sc[tm][tn][r] * 0.125f);
                    rs += p;
                    Ps[row * PS + tn * 16 + l16] = (short)__bfloat16_as_ushort(f2bf(p));
                }
                lsum[tm][r] += rs;
            }
        }
        // no barrier: Ps rows [wq, wq+32) are written and read by this wave only

        // PV: O[32 x 64] per wave
        __builtin_amdgcn_s_setprio(1);
#pragma unroll
        for (int ks = 0; ks < 64; ks += 32) {
            bf16x8_t ap[2], bv[4];
#pragma unroll
            for (int tm = 0; tm < 2; ++tm)
                ap[tm] = *(const bf16x8_t*)&Ps[(wq + tm * 16 + l16) * PS + ks + quad * 8];
#pragma unroll
            for (int tn = 0; tn < 4; ++tn)
                bv[tn] = *(const bf16x8_t*)&Vt[cur][(tn * 16 + l16) * VS + ks + quad * 8];
#pragma unroll
            for (int tm = 0; tm < 2; ++tm)
#pragma unroll
                for (int tn = 0; tn < 4; ++tn)
                    Oacc[tm][tn] = __builtin_amdgcn_mfma_f32_16x16x32_bf16(
                        ap[tm], bv[tn], Oacc[tm][tn], 0, 0, 0);
        }
        __builtin_amdgcn_s_setprio(0);

        if (kt < 7) {
#pragma unroll
            for (int i = 0; i < 8; ++i) {
                Vt[nxt][(w * 16 + i) * VS + lane]     = pv0[i];
                Vt[nxt][(w * 16 + 8 + i) * VS + lane] = pv1[i];
            }
        }
        __syncthreads();
    }

    // reduce row sums across 16 col-lanes, normalize, store
    float linv[2][4];
#pragma unroll
    for (int tm = 0; tm < 2; ++tm)
#pragma unroll
        for (int r = 0; r < 4; ++r) {
            float v = lsum[tm][r];
            v += __shfl_xor(v, 1, 64);
            v += __shfl_xor(v, 2, 64);
            v += __shfl_xor(v, 4, 64);
            v += __shfl_xor(v, 8, 64);
            linv[tm][r] = 1.f / v;
        }
    const int b = bh / H_, h = bh % H_;
#pragma unroll
    for (int tm = 0; tm < 2; ++tm) {
#pragma unroll
        for (int r = 0; r < 4; ++r) {
            int row = q0 + wq + tm * 16 + quad * 4 + r;
            size_t ob = ((size_t)b * S_ + row) * D_ + h * HD_;
#pragma unroll
            for (int tn = 0; tn < 4; ++tn)
                O[ob + tn * 16 + l16] = f2bf(Oacc[tm][tn][r] * linv[tm][r]);
        }
    }
}

// ---------------------------------------------------------------------------
extern "C" void kernel_launch(void* const* d_in, const int* in_sizes, int n_in,
                              void* d_out, int out_size, void* d_ws, size_t ws_size,
                              hipStream_t stream) {
    const float* x      = (const float*)d_in[0];
    const float* qkv_w  = (const float*)d_in[1];
    const float* qkv_b  = (const float*)d_in[2];
    const float* proj_w = (const float*)d_in[3];
    const float* proj_b = (const float*)d_in[4];
    float* out = (float*)d_out;

    unsigned short* q     = (unsigned short*)d_ws;
    unsigned short* k     = q + QKV_ELEMS;
    unsigned short* v     = k + QKV_ELEMS;
    unsigned short* slot4 = v + QKV_ELEMS;          // x_bf, then attn-out
    unsigned short* wq    = slot4 + QKV_ELEMS;
    unsigned short* wp    = wq + 2304 * 768;

    // single fused conversion launch: 12288 + 1728 + 576 = 14592 blocks
    const int nx = 16384 * 768 / 4, nw1 = 2304 * 768 / 4, nw2 = 768 * 768 / 4;
    f2bf3_kernel<<<(nx + nw1 + nw2 + 255) / 256, 256, 0, stream>>>(
        x, slot4, nx, qkv_w, wq, nw1, proj_w, wp, nw2);

    qkv_gemm_mfma<<<dim3(2304), 256, 0, stream>>>(
        (const short*)slot4, (const short*)wq, qkv_b,
        (bf16*)q, (bf16*)k, (bf16*)v);

    attn_mfma<<<dim3(32 * 12 * 4), 256, 0, stream>>>(
        (const short*)q, (const short*)k, (const short*)v, (bf16*)slot4);

    proj_gemm_mfma<<<dim3(768), 256, 0, stream>>>(
        (const short*)slot4, (const short*)wp, proj_b, out);
}

// Round 14
// 239.261 us; speedup vs baseline: 1.2409x; 1.0168x over previous
//
#include <hip/hip_runtime.h>
#include <hip/hip_bf16.h>

#define B_  32
#define S_  512
#define D_  768
#define H_  12
#define HD_ 64
#define QKV_ELEMS (B_ * H_ * S_ * HD_)  // 12582912 per tensor

typedef __hip_bfloat16 bf16;
typedef short bf16x8_t __attribute__((ext_vector_type(8)));
typedef float f32x4_t  __attribute__((ext_vector_type(4)));

__device__ __forceinline__ float bf2f(bf16 x) { return __bfloat162float(x); }
__device__ __forceinline__ bf16  f2bf(float x) { return __float2bfloat16(x); }

__device__ __forceinline__ void gl_lds16(const short* g, short* l) {
    __builtin_amdgcn_global_load_lds(
        (const __attribute__((address_space(1))) void*)g,
        (__attribute__((address_space(3))) void*)l, 16, 0, 0);
}

// ---------------------------------------------------------------------------
// fused fp32 -> bf16 conversion for all three tensors in ONE launch.
// (r12 lesson: standalone BW-bound pass beats in-GEMM sync fusion.)
// ---------------------------------------------------------------------------
__global__ __launch_bounds__(256) void f2bf3_kernel(
    const float* __restrict__ in0, unsigned short* __restrict__ out0, int n0,
    const float* __restrict__ in1, unsigned short* __restrict__ out1, int n1,
    const float* __restrict__ in2, unsigned short* __restrict__ out2, int n2)
{
    int i = blockIdx.x * 256 + threadIdx.x;
    const float* in; unsigned short* out;
    if (i < n0)           { in = in0; out = out0; }
    else if (i < n0 + n1) { in = in1; out = out1; i -= n0; }
    else                  { in = in2; out = out2; i -= n0 + n1;
                            if (i >= n2) return; }
    float4 v = reinterpret_cast<const float4*>(in)[i];
    ushort4 o;
    o.x = __bfloat16_as_ushort(f2bf(v.x));
    o.y = __bfloat16_as_ushort(f2bf(v.y));
    o.z = __bfloat16_as_ushort(f2bf(v.z));
    o.w = __bfloat16_as_ushort(f2bf(v.w));
    reinterpret_cast<ushort4*>(out)[i] = o;
}

// ---------------------------------------------------------------------------
// MFMA GEMM core — single-buffered (r9/r11/r13 measured-best, FROZEN).
// Permanent lessons: gl_lds IS the coalescing mechanism (r10); async staging
// only (r12); (256,4) bound — (256,5) spills (r8); single-buffer 4-blk/CU
// beats dbuf 2-blk/CU at K=768 (r9 vs r6).
// ---------------------------------------------------------------------------
#define GEMM_CORE(As, Bs, Aptr, Bptr, m0, n0, K)                               \
    const int t = threadIdx.x;                                                 \
    const int w = t >> 6, lane = t & 63;                                       \
    const int wr = w >> 1, wc = w & 1;                                         \
    const int quad = lane >> 4, l16 = lane & 15;                               \
    f32x4_t acc[4][4] = {};                                                    \
    const int lrow = lane >> 3;                                                \
    const int scol = (((lane & 7) ^ (lrow & 7)) * 8);                          \
    _Pragma("unroll")                                                          \
    for (int j = 0; j < 4; ++j) {                                              \
        int R = j * 32 + w * 8;                                                \
        gl_lds16((Aptr) + (size_t)((m0) + R + lrow) * (K) + scol, &(As)[R * 64]); \
        gl_lds16((Bptr) + (size_t)((n0) + R + lrow) * (K) + scol, &(Bs)[R * 64]); \
    }                                                                          \
    for (int k0 = 0; k0 < (K); k0 += 64) {                                     \
        __syncthreads();   /* implicit vmcnt drain: tile k0 resident */        \
        _Pragma("unroll")                                                      \
        for (int ks = 0; ks < 64; ks += 32) {                                  \
            bf16x8_t af[4], bf_[4];                                            \
            _Pragma("unroll")                                                  \
            for (int tm = 0; tm < 4; ++tm)                                     \
                af[tm] = *(const bf16x8_t*)&(As)[(wr * 64 + tm * 16 + l16) * 64 \
                        + ((((ks >> 3) + quad) ^ (l16 & 7)) * 8)];             \
            _Pragma("unroll")                                                  \
            for (int tn = 0; tn < 4; ++tn)                                     \
                bf_[tn] = *(const bf16x8_t*)&(Bs)[(wc * 64 + tn * 16 + l16) * 64 \
                        + ((((ks >> 3) + quad) ^ (l16 & 7)) * 8)];             \
            _Pragma("unroll")                                                  \
            for (int tm = 0; tm < 4; ++tm)                                     \
                _Pragma("unroll")                                              \
                for (int tn = 0; tn < 4; ++tn)                                 \
                    acc[tm][tn] = __builtin_amdgcn_mfma_f32_16x16x32_bf16(     \
                        af[tm], bf_[tn], acc[tm][tn], 0, 0, 0);                \
        }                                                                      \
        __syncthreads();   /* all waves done reading tile k0 */                \
        if (k0 + 64 < (K)) {                                                   \
            _Pragma("unroll")                                                  \
            for (int j = 0; j < 4; ++j) {                                      \
                int R = j * 32 + w * 8;                                        \
                gl_lds16((Aptr) + (size_t)((m0) + R + lrow) * (K) + k0 + 64 + scol, \
                         &(As)[R * 64]);                                       \
                gl_lds16((Bptr) + (size_t)((n0) + R + lrow) * (K) + k0 + 64 + scol, \
                         &(Bs)[R * 64]);                                       \
            }                                                                  \
        }                                                                      \
    }

// ---------------------------------------------------------------------------
// Kernel 1: QKV projection -> q/k/v in [B,H,S,HD] bf16.  (FROZEN at r13)
// ---------------------------------------------------------------------------
__global__ __launch_bounds__(256, 4) void qkv_gemm_mfma(
    const short* __restrict__ A, const short* __restrict__ W,
    const float* __restrict__ bias,
    bf16* __restrict__ Q, bf16* __restrict__ Kp, bf16* __restrict__ Vp)
{
    __shared__ short As[128 * 64];   // 16 KB
    __shared__ short Bs[128 * 64];   // 16 KB
    const int bid = blockIdx.x;
    const int swz = (bid & 7) * (2304 / 8) + (bid >> 3);
    const int n0 = (swz % 18) * 128;
    const int m0 = (swz / 18) * 128;
    GEMM_CORE(As, Bs, A, W, m0, n0, 768)

    const int which = n0 / 768;
    const int h = ((n0 + wc * 64) % 768) >> 6;
    bf16* dst = (which == 0) ? Q : (which == 1) ? Kp : Vp;
    float bv[4];
#pragma unroll
    for (int tn = 0; tn < 4; ++tn) bv[tn] = bias[n0 + wc * 64 + tn * 16 + l16];
#pragma unroll
    for (int tm = 0; tm < 4; ++tm) {
#pragma unroll
        for (int r = 0; r < 4; ++r) {
            int m = m0 + wr * 64 + tm * 16 + quad * 4 + r;
            int b = m >> 9, s = m & 511;
            size_t rb = (((size_t)b * H_ + h) * S_ + s) * HD_;
#pragma unroll
            for (int tn = 0; tn < 4; ++tn)
                dst[rb + tn * 16 + l16] = f2bf(acc[tm][tn][r] + bv[tn]);
        }
    }
}

// ---------------------------------------------------------------------------
// Kernel 3: output projection, fp32 out.  (FROZEN at r13)
// ---------------------------------------------------------------------------
__global__ __launch_bounds__(256, 4) void proj_gemm_mfma(
    const short* __restrict__ A, const short* __restrict__ W,
    const float* __restrict__ bias, float* __restrict__ out)
{
    __shared__ short As[128 * 64];
    __shared__ short Bs[128 * 64];
    const int bid = blockIdx.x;
    const int swz = (bid & 7) * (768 / 8) + (bid >> 3);
    const int n0 = (swz % 6) * 128;
    const int m0 = (swz / 6) * 128;
    GEMM_CORE(As, Bs, A, W, m0, n0, 768)

    float bv[4];
#pragma unroll
    for (int tn = 0; tn < 4; ++tn) bv[tn] = bias[n0 + wc * 64 + tn * 16 + l16];
#pragma unroll
    for (int tm = 0; tm < 4; ++tm) {
#pragma unroll
        for (int r = 0; r < 4; ++r) {
            int m = m0 + wr * 64 + tm * 16 + quad * 4 + r;
#pragma unroll
            for (int tn = 0; tn < 4; ++tn)
                out[(size_t)m * 768 + n0 + wc * 64 + tn * 16 + l16] =
                    acc[tm][tn][r] + bv[tn];
        }
    }
}

// ---------------------------------------------------------------------------
// Kernel 2: MFMA flash attention — 8-WAVE variant (round-13 change).
// Same QT=128 tile, same LDS (50 KB -> 3 blocks/CU), same verified layouts
// (chunk-XOR K swizzle, wave-private Ps rows, Vt [dim][key] stride 68,
// pipelined K/V double-buffer).  Change: 512 threads = 8 waves, each wave
// owns 16 q-rows (wq = w*16, tm dimension eliminated) -> waves/CU 12 -> 24,
// doubling the scheduler's ability to overlap exp-VALU with MFMA and hide
// the sync V-reg load (same TLP lever that won r9 for qkv).  Per-thread
// registers drop ~half (Oacc 32->16 AGPR, aq 16->8 VGPR).
// (512,4) bound = VGPR cap 128: guaranteed no spill (r8 lesson); occupancy
// is LDS-bound at 3 blocks/CU regardless.
// ---------------------------------------------------------------------------
#define QT 128
#define KT 64
#define PS 68
#define VS 68

__global__ __launch_bounds__(512, 4) void attn_mfma(
    const short* __restrict__ Qg, const short* __restrict__ Kg,
    const short* __restrict__ Vg, bf16* __restrict__ O)
{
    __shared__ short Ks[2][KT * 64];   // 16 KB
    __shared__ short Vt[2][64 * VS];   // 17 KB  [dim][key]
    __shared__ short Ps[QT * PS];      // 17 KB

    const int t = threadIdx.x;
    const int w = t >> 6, lane = t & 63;        // w in 0..7
    const int quad = lane >> 4, l16 = lane & 15;
    const int lrow = lane >> 3;
    const int scol = (((lane & 7) ^ (lrow & 7)) * 8);
    const int bid = blockIdx.x;
    const int bh = (bid & 7) + 8 * (bid >> 5);  // 4 q-tiles of a bh share an XCD
    const int qt = (bid >> 3) & 3;
    const int q0 = qt * QT;
    const size_t base = (size_t)bh * (S_ * HD_);
    const int wq = w * 16;                      // 16 q-rows per wave

    // Q fragments: direct global->reg, loop-invariant (8 VGPRs).
    bf16x8_t aq[2];
#pragma unroll
    for (int ksi = 0; ksi < 2; ++ksi)
        aq[ksi] = *(const bf16x8_t*)(Qg + base
            + (size_t)(q0 + wq + l16) * 64 + ksi * 32 + quad * 8);

    f32x4_t Oacc[4] = {};
    float lsum[4] = {};

    // prologue: stage K0 (one gl_lds16 per wave: rows w*8..w*8+7, swizzled)
    // + V0 global->reg->Vt[0] (each wave stages 8 dims)
    gl_lds16(Kg + base + (size_t)(w * 8 + lrow) * 64 + scol, &Ks[0][w * 8 * 64]);
    {
        bf16x8_t v0 = *(const bf16x8_t*)(Vg + base + (size_t)lane * 64 + w * 8);
#pragma unroll
        for (int i = 0; i < 8; ++i)
            Vt[0][(w * 8 + i) * VS + lane] = v0[i];
    }
    __syncthreads();

    for (int kt = 0; kt < 8; ++kt) {
        const int cur = kt & 1, nxt = cur ^ 1;
        bf16x8_t pv = {};
        if (kt < 7) {
            // issue next tile's loads NOW; latency hides under this tile's
            // compute (and under the other 23 waves on the CU).
            gl_lds16(Kg + base + (size_t)((kt + 1) * KT + w * 8 + lrow) * 64 + scol,
                     &Ks[nxt][w * 8 * 64]);
            pv = *(const bf16x8_t*)(Vg + base
                + (size_t)((kt + 1) * KT + lane) * 64 + w * 8);
        }

        // QK^T: per-wave S tile [16 queries x 64 keys]
        f32x4_t sc[4] = {};
        __builtin_amdgcn_s_setprio(1);
#pragma unroll
        for (int ks = 0; ks < 64; ks += 32) {
            bf16x8_t bk[4];
#pragma unroll
            for (int tn = 0; tn < 4; ++tn)
                bk[tn] = *(const bf16x8_t*)&Ks[cur][(tn * 16 + l16) * 64
                        + ((((ks >> 3) + quad) ^ (l16 & 7)) * 8)];
#pragma unroll
            for (int tn = 0; tn < 4; ++tn)
                sc[tn] = __builtin_amdgcn_mfma_f32_16x16x32_bf16(
                    aq[ks >> 5], bk[tn], sc[tn], 0, 0, 0);
        }
        __builtin_amdgcn_s_setprio(0);

        // p = exp(s * 0.125); per-lane row partials; P -> LDS bf16
#pragma unroll
        for (int r = 0; r < 4; ++r) {
            int row = wq + quad * 4 + r;
            float rs = 0.f;
#pragma unroll
            for (int tn = 0; tn < 4; ++tn) {
                float p = __expf(sc[tn][r] * 0.125f);
                rs += p;
                Ps[row * PS + tn * 16 + l16] = (short)__bfloat16_as_ushort(f2bf(p));
            }
            lsum[r] += rs;
        }
        // no barrier: Ps rows [wq, wq+16) are written and read by this wave only

        // PV: O[16 x 64] per wave
        __builtin_amdgcn_s_setprio(1);
#pragma unroll
        for (int ks = 0; ks < 64; ks += 32) {
            bf16x8_t ap, bv[4];
            ap = *(const bf16x8_t*)&Ps[(wq + l16) * PS + ks + quad * 8];
#pragma unroll
            for (int tn = 0; tn < 4; ++tn)
                bv[tn] = *(const bf16x8_t*)&Vt[cur][(tn * 16 + l16) * VS + ks + quad * 8];
#pragma unroll
            for (int tn = 0; tn < 4; ++tn)
                Oacc[tn] = __builtin_amdgcn_mfma_f32_16x16x32_bf16(
                    ap, bv[tn], Oacc[tn], 0, 0, 0);
        }
        __builtin_amdgcn_s_setprio(0);

        // write next tile's V transpose from regs (loads long since landed),
        // then the single per-tile barrier.
        if (kt < 7) {
#pragma unroll
            for (int i = 0; i < 8; ++i)
                Vt[nxt][(w * 8 + i) * VS + lane] = pv[i];
        }
        __syncthreads();
    }

    // reduce row sums across 16 col-lanes, normalize, store
    float linv[4];
#pragma unroll
    for (int r = 0; r < 4; ++r) {
        float v = lsum[r];
        v += __shfl_xor(v, 1, 64);
        v += __shfl_xor(v, 2, 64);
        v += __shfl_xor(v, 4, 64);
        v += __shfl_xor(v, 8, 64);
        linv[r] = 1.f / v;
    }
    const int b = bh / H_, h = bh % H_;
#pragma unroll
    for (int r = 0; r < 4; ++r) {
        int row = q0 + wq + quad * 4 + r;
        size_t ob = ((size_t)b * S_ + row) * D_ + h * HD_;
#pragma unroll
        for (int tn = 0; tn < 4; ++tn)
            O[ob + tn * 16 + l16] = f2bf(Oacc[tn][r] * linv[r]);
    }
}

// ---------------------------------------------------------------------------
extern "C" void kernel_launch(void* const* d_in, const int* in_sizes, int n_in,
                              void* d_out, int out_size, void* d_ws, size_t ws_size,
                              hipStream_t stream) {
    const float* x      = (const float*)d_in[0];
    const float* qkv_w  = (const float*)d_in[1];
    const float* qkv_b  = (const float*)d_in[2];
    const float* proj_w = (const float*)d_in[3];
    const float* proj_b = (const float*)d_in[4];
    float* out = (float*)d_out;

    unsigned short* q     = (unsigned short*)d_ws;
    unsigned short* k     = q + QKV_ELEMS;
    unsigned short* v     = k + QKV_ELEMS;
    unsigned short* slot4 = v + QKV_ELEMS;          // x_bf, then attn-out
    unsigned short* wq    = slot4 + QKV_ELEMS;
    unsigned short* wp    = wq + 2304 * 768;

    // single fused conversion launch: 12288 + 1728 + 576 = 14592 blocks
    const int nx = 16384 * 768 / 4, nw1 = 2304 * 768 / 4, nw2 = 768 * 768 / 4;
    f2bf3_kernel<<<(nx + nw1 + nw2 + 255) / 256, 256, 0, stream>>>(
        x, slot4, nx, qkv_w, wq, nw1, proj_w, wp, nw2);

    qkv_gemm_mfma<<<dim3(2304), 256, 0, stream>>>(
        (const short*)slot4, (const short*)wq, qkv_b,
        (bf16*)q, (bf16*)k, (bf16*)v);

    attn_mfma<<<dim3(32 * 12 * 4), 512, 0, stream>>>(
        (const short*)q, (const short*)k, (const short*)v, (bf16*)slot4);

    proj_gemm_mfma<<<dim3(768), 256, 0, stream>>>(
        (const short*)slot4, (const short*)wp, proj_b, out);
}